// Round 5
// baseline (170.613 us; speedup 1.0000x reference)
//
#include <hip/hip_runtime.h>
#include <hip/hip_bf16.h>
#include <stdint.h>

#define NN 1024
#define EMBED 256
#define NHEAD 8
#define NHID 32
#define SLOPE 0.2f

// Grid-barrier counters. __device__ globals are zeroed at module load and are
// NOT poisoned by the harness (only d_out/d_ws are). The kernel self-resets
// them at the end of every launch (last-to-arrive resets), so every launch
// (correctness call, capture, each replay) sees zeros. Deterministic.
__device__ unsigned int g_barA;   // after GEMM + adj-zero
__device__ unsigned int g_barC;   // after edge scatter
__device__ unsigned int g_barB;   // exit counter (reset trigger)

__device__ __forceinline__ void grid_barrier(unsigned int* ctr, int t) {
    __threadfence();              // release: writeback L1/L2 (cross-XCD visibility)
    __syncthreads();
    if (t == 0) {
        __hip_atomic_fetch_add(ctr, 1u, __ATOMIC_ACQ_REL, __HIP_MEMORY_SCOPE_AGENT);
        while (__hip_atomic_load(ctr, __ATOMIC_ACQUIRE, __HIP_MEMORY_SCOPE_AGENT) < 256u) {}
    }
    __syncthreads();
    __threadfence();              // acquire: invalidate stale L1/L2 lines
}

// One persistent kernel, 256 blocks x 256 threads (1 block/CU -> co-resident).
// Phase 1a: zero own adj slice + GEMM 32x64 tile (gl|gr selected by blk&1).
// barrier A. Phase 1b: scatter edges into adj via global atomicOr (dedupes).
// barrier C. Phase 2: 4 destination rows per block, 4 parallel online-softmax
// streams per thread (thread t owns feature t; head = t/32, dim = t%32).
__global__ __launch_bounds__(256) void k_fused(const float* __restrict__ h,
                                               const float* __restrict__ Wl,
                                               const float* __restrict__ Wr,
                                               const int* __restrict__ ei, int E,
                                               const float* __restrict__ attn_w,
                                               float* __restrict__ gl,
                                               float* __restrict__ gr,
                                               unsigned int* __restrict__ adj,
                                               float* __restrict__ out) {
    const int blk = blockIdx.x;
    const int t = threadIdx.x;

    __shared__ float As[16][33];     // [k][m], padded
    __shared__ float Bs[16][68];     // [k][n], padded
    __shared__ int nbr[4][256];      // neighbor lists for the block's 4 rows
    __shared__ int cnt_s[4];

    // ---------------- phase 1a: zero adj slice (128 words/block) -------------
    if (t < 128) adj[blk * 128 + t] = 0u;

    // ---------------- phase 1a: GEMM 32x64 tile ------------------------------
    {
        const int z  = blk & 1;
        const int bn = ((blk >> 1) & 3) * 64;
        const int bm = (blk >> 3) * 32;
        const float* W = z ? Wr : Wl;
        float* outg = z ? gr : gl;
        const int tx = t & 15;
        const int ty = t >> 4;

        float acc[2][4];
#pragma unroll
        for (int i = 0; i < 2; ++i)
#pragma unroll
            for (int j = 0; j < 4; ++j) acc[i][j] = 0.f;

        const int ar = t >> 2, ac = (t & 3) << 2;    // A loader (t<128)
        const int br = t >> 4, bc = (t & 15) << 2;   // B loader (all)
        const float* Ap = &h[(bm + ar) * EMBED + ac];
        const float* Bp = &W[br * EMBED + bn + bc];

        float4 a_reg = make_float4(0.f, 0.f, 0.f, 0.f);
        if (t < 128) a_reg = *reinterpret_cast<const float4*>(Ap);
        float4 b_reg = *reinterpret_cast<const float4*>(Bp);

        for (int k0 = 0; k0 < EMBED; k0 += 16) {
            if (t < 128) {
                As[ac + 0][ar] = a_reg.x; As[ac + 1][ar] = a_reg.y;
                As[ac + 2][ar] = a_reg.z; As[ac + 3][ar] = a_reg.w;
            }
            Bs[br][bc + 0] = b_reg.x; Bs[br][bc + 1] = b_reg.y;
            Bs[br][bc + 2] = b_reg.z; Bs[br][bc + 3] = b_reg.w;
            __syncthreads();
            if (k0 + 16 < EMBED) {   // register-prefetch next K tile
                if (t < 128) a_reg = *reinterpret_cast<const float4*>(Ap + k0 + 16);
                b_reg = *reinterpret_cast<const float4*>(Bp + (size_t)(k0 + 16) * EMBED);
            }
#pragma unroll
            for (int kk = 0; kk < 16; ++kk) {
                float a0 = As[kk][ty * 2 + 0];
                float a1 = As[kk][ty * 2 + 1];
                float b0 = Bs[kk][tx * 4 + 0];
                float b1 = Bs[kk][tx * 4 + 1];
                float b2 = Bs[kk][tx * 4 + 2];
                float b3 = Bs[kk][tx * 4 + 3];
                acc[0][0] += a0 * b0; acc[0][1] += a0 * b1;
                acc[0][2] += a0 * b2; acc[0][3] += a0 * b3;
                acc[1][0] += a1 * b0; acc[1][1] += a1 * b1;
                acc[1][2] += a1 * b2; acc[1][3] += a1 * b3;
            }
            __syncthreads();
        }
#pragma unroll
        for (int i = 0; i < 2; ++i) {
            float4 v = make_float4(acc[i][0], acc[i][1], acc[i][2], acc[i][3]);
            *reinterpret_cast<float4*>(&outg[(bm + ty * 2 + i) * EMBED + bn + tx * 4]) = v;
        }
    }

    grid_barrier(&g_barA, t);   // zeros + gemm visible everywhere

    // ---------------- phase 1b: scatter edges (global atomicOr) --------------
    {
        const int nvec = E >> 1;
        const int4* ei4 = reinterpret_cast<const int4*>(ei);
        if (t < 64) {
            for (int idx = blk * 64 + t; idx < nvec; idx += 256 * 64) {
                int4 v = ei4[idx];
                atomicOr(&adj[v.x * 32 + ((unsigned)v.y >> 5)], 1u << (v.y & 31));
                atomicOr(&adj[v.z * 32 + ((unsigned)v.w >> 5)], 1u << (v.w & 31));
            }
        }
        if ((E & 1) && blk == 0 && t == 64) {
            int r = ei[2 * (E - 1)], c = ei[2 * (E - 1) + 1];
            atomicOr(&adj[r * 32 + ((unsigned)c >> 5)], 1u << (c & 31));
        }
    }

    grid_barrier(&g_barC, t);   // adjacency complete

    // ---------------- phase 2: attention, 4 rows per block -------------------
    const int rbase = blk * 4;
    {
        // wave wv compacts row rbase+wv: popc prefix over 64 lanes
        const int wv = t >> 6, lane = t & 63;
        unsigned int w = (lane < 32) ? adj[(rbase + wv) * 32 + lane] : 0u;
        int c = __popc(w);
        int pre = c;
#pragma unroll
        for (int d = 1; d < 64; d <<= 1) {
            int v = __shfl_up(pre, d);
            if (lane >= d) pre += v;
        }
        int off = pre - c;            // exclusive prefix
        if (lane == 63) cnt_s[wv] = pre;
        while (w) {
            int b = __builtin_ctz(w);
            w &= w - 1;
            if (off < 256) nbr[wv][off] = lane * 32 + b;
            ++off;
        }
    }
    __syncthreads();

    int cnt[4];
    float grv[4], m[4], s[4], acc[4];
    const float aw = attn_w[t & 31];
    int cmax = 0;
#pragma unroll
    for (int u = 0; u < 4; ++u) {
        cnt[u] = cnt_s[u];
        cmax = cnt[u] > cmax ? cnt[u] : cmax;
        grv[u] = gr[(rbase + u) * EMBED + t];
        m[u] = -3e38f; s[u] = 0.f; acc[u] = 0.f;
    }

    // depth-2 prefetch per stream (8 loads in flight)
    float g0[4], g1[4];
#pragma unroll
    for (int u = 0; u < 4; ++u) {
        g0[u] = gl[nbr[u][0] * EMBED + t];
        int e1 = (1 < cnt[u]) ? 1 : 0;
        g1[u] = gl[nbr[u][e1] * EMBED + t];
    }

    for (int e = 0; e < cmax; ++e) {
        float cur[4];
#pragma unroll
        for (int u = 0; u < 4; ++u) cur[u] = g0[u];
#pragma unroll
        for (int u = 0; u < 4; ++u) {
            g0[u] = g1[u];
            int e2 = (e + 2 < cnt[u]) ? e + 2 : cnt[u] - 1;
            g1[u] = gl[nbr[u][e2] * EMBED + t];
        }
#pragma unroll
        for (int u = 0; u < 4; ++u) {
            float x = cur[u] + grv[u];
            float pv = (x > 0.f ? x : SLOPE * x) * aw;
            pv += __shfl_xor(pv, 1);
            pv += __shfl_xor(pv, 2);
            pv += __shfl_xor(pv, 4);
            pv += __shfl_xor(pv, 8);
            pv += __shfl_xor(pv, 16);
            if (e < cnt[u]) {
                float mn = fmaxf(m[u], pv);
                float sc = __expf(m[u] - mn);
                float ev = __expf(pv - mn);
                s[u] = s[u] * sc + ev;
                acc[u] = acc[u] * sc + ev * cur[u];
                m[u] = mn;
            }
        }
    }
#pragma unroll
    for (int u = 0; u < 4; ++u)
        out[(rbase + u) * EMBED + t] = acc[u] / s[u];

    // ---------------- exit: last block resets barrier counters ---------------
    __syncthreads();
    if (t == 0) {
        unsigned int old = __hip_atomic_fetch_add(&g_barB, 1u, __ATOMIC_ACQ_REL,
                                                  __HIP_MEMORY_SCOPE_AGENT);
        if (old == 255u) {
            __hip_atomic_store(&g_barA, 0u, __ATOMIC_RELAXED, __HIP_MEMORY_SCOPE_AGENT);
            __hip_atomic_store(&g_barC, 0u, __ATOMIC_RELAXED, __HIP_MEMORY_SCOPE_AGENT);
            __hip_atomic_store(&g_barB, 0u, __ATOMIC_RELEASE, __HIP_MEMORY_SCOPE_AGENT);
        }
    }
}

extern "C" void kernel_launch(void* const* d_in, const int* in_sizes, int n_in,
                              void* d_out, int out_size, void* d_ws, size_t ws_size,
                              hipStream_t stream) {
    const float* h  = (const float*)d_in[0];
    const int*   ei = (const int*)d_in[1];
    const float* Wl = (const float*)d_in[2];
    const float* Wr = (const float*)d_in[3];
    const float* aw = (const float*)d_in[4];
    float* out = (float*)d_out;
    const int E = in_sizes[1] / 2;

    unsigned int* adj = (unsigned int*)d_ws;                 // 128 KB
    float* gl = (float*)((char*)d_ws + 131072);              // 1 MB
    float* gr = gl + NN * EMBED;                             // 1 MB

    k_fused<<<256, 256, 0, stream>>>(h, Wl, Wr, ei, E, aw, gl, gr, adj, out);
}

// Round 6
// 38.356 us; speedup vs baseline: 4.4481x; 4.4481x over previous
//
#include <hip/hip_runtime.h>
#include <hip/hip_bf16.h>
#include <stdint.h>

#define NN 1024
#define EMBED 256
#define NHEAD 8
#define NHID 32
#define SLOPE 0.2f

// ---------------------------------------------------------------------------
// Kernel 1, grid 288:
//   blocks [0,256)  : GEMM 32x64 tile of {gl|gr} = h @ {W_l|W_r}, reg-prefetch
//   blocks [256,288): adjacency bitmask, 32 rows/block via LDS accumulation
// ---------------------------------------------------------------------------
__global__ __launch_bounds__(256) void k_prep(const float* __restrict__ h,
                                              const float* __restrict__ Wl,
                                              const float* __restrict__ Wr,
                                              const int* __restrict__ ei, int E,
                                              float* __restrict__ gl,
                                              float* __restrict__ gr,
                                              unsigned int* __restrict__ adj) {
    const int blk = blockIdx.x;
    const int t = threadIdx.x;

    if (blk < 256) {
        const int z  = blk & 1;
        const int bn = ((blk >> 1) & 3) * 64;
        const int bm = (blk >> 3) * 32;
        const float* W = z ? Wr : Wl;
        float* outg = z ? gr : gl;
        const int tx = t & 15;
        const int ty = t >> 4;

        __shared__ float As[16][33];     // [k][m]
        __shared__ float Bs[16][68];     // [k][n], 16B-aligned rows

        float acc[2][4];
#pragma unroll
        for (int i = 0; i < 2; ++i)
#pragma unroll
            for (int j = 0; j < 4; ++j) acc[i][j] = 0.f;

        const int ar = t >> 2, ac = (t & 3) << 2;    // A loader (t<128): 32x16
        const int br = t >> 4, bc = (t & 15) << 2;   // B loader (all): 16x64
        const float* Ap = &h[(bm + ar) * EMBED + ac];
        const float* Bp = &W[br * EMBED + bn + bc];

        float4 a_reg = make_float4(0.f, 0.f, 0.f, 0.f);
        if (t < 128) a_reg = *reinterpret_cast<const float4*>(Ap);
        float4 b_reg = *reinterpret_cast<const float4*>(Bp);

        for (int k0 = 0; k0 < EMBED; k0 += 16) {
            if (t < 128) {
                As[ac + 0][ar] = a_reg.x; As[ac + 1][ar] = a_reg.y;
                As[ac + 2][ar] = a_reg.z; As[ac + 3][ar] = a_reg.w;
            }
            Bs[br][bc + 0] = b_reg.x; Bs[br][bc + 1] = b_reg.y;
            Bs[br][bc + 2] = b_reg.z; Bs[br][bc + 3] = b_reg.w;
            __syncthreads();
            if (k0 + 16 < EMBED) {   // register-prefetch next K tile
                if (t < 128) a_reg = *reinterpret_cast<const float4*>(Ap + k0 + 16);
                b_reg = *reinterpret_cast<const float4*>(Bp + (size_t)(k0 + 16) * EMBED);
            }
#pragma unroll
            for (int kk = 0; kk < 16; ++kk) {
                float a0 = As[kk][ty * 2 + 0];
                float a1 = As[kk][ty * 2 + 1];
                float b0 = Bs[kk][tx * 4 + 0];
                float b1 = Bs[kk][tx * 4 + 1];
                float b2 = Bs[kk][tx * 4 + 2];
                float b3 = Bs[kk][tx * 4 + 3];
                acc[0][0] += a0 * b0; acc[0][1] += a0 * b1;
                acc[0][2] += a0 * b2; acc[0][3] += a0 * b3;
                acc[1][0] += a1 * b0; acc[1][1] += a1 * b1;
                acc[1][2] += a1 * b2; acc[1][3] += a1 * b3;
            }
            __syncthreads();
        }
#pragma unroll
        for (int i = 0; i < 2; ++i) {
            float4 v = make_float4(acc[i][0], acc[i][1], acc[i][2], acc[i][3]);
            *reinterpret_cast<float4*>(&outg[(bm + ty * 2 + i) * EMBED + bn + tx * 4]) = v;
        }
    } else {
        // adjacency build: rows [lo, lo+32), 1024 uint words in LDS
        const int lo = (blk - 256) * 32;
        __shared__ unsigned int lads[1024];
#pragma unroll
        for (int u = 0; u < 4; ++u) lads[t + u * 256] = 0u;
        __syncthreads();

        const int4* ei4 = reinterpret_cast<const int4*>(ei);  // 2 edges / int4
        const int nvec = E >> 1;                              // 16384
        for (int base = 0; base < nvec; base += 2048) {
#pragma unroll 8
            for (int u = 0; u < 8; ++u) {
                int4 v = ei4[base + u * 256 + t];
                int r0 = v.x - lo;
                if ((unsigned)r0 < 32u)
                    atomicOr(&lads[r0 * 32 + ((unsigned)v.y >> 5)], 1u << (v.y & 31));
                int r1 = v.z - lo;
                if ((unsigned)r1 < 32u)
                    atomicOr(&lads[r1 * 32 + ((unsigned)v.w >> 5)], 1u << (v.w & 31));
            }
        }
        __syncthreads();
#pragma unroll
        for (int u = 0; u < 4; ++u)
            adj[lo * 32 + t + u * 256] = lads[t + u * 256];
    }
}

// ---------------------------------------------------------------------------
// Kernel 2: per-destination-row sparse softmax + aggregate (1 row / block).
// Thread t owns feature f=t (head t/32, dim t%32). Wave 0 compacts the set
// bits into an LDS neighbor list, then unroll-4 online softmax with
// one-group-ahead prefetch.
// ---------------------------------------------------------------------------
__global__ __launch_bounds__(256) void k_attn(const float* __restrict__ gl,
                                              const float* __restrict__ gr,
                                              const unsigned int* __restrict__ adj,
                                              const float* __restrict__ attn_w,
                                              float* __restrict__ out) {
    const int i = blockIdx.x;
    const int t = threadIdx.x;

    __shared__ int nbr[NN];
    __shared__ int cnt_s;

    if (t < 64) {
        unsigned int w = (t < 32) ? adj[i * 32 + t] : 0u;
        int c = __popc(w);
        int pre = c;
#pragma unroll
        for (int d = 1; d < 64; d <<= 1) {
            int v = __shfl_up(pre, d);
            if (t >= d) pre += v;
        }
        int off = pre - c;          // exclusive prefix
        if (t == 63) cnt_s = pre;   // total count
        while (w) {
            int b = __builtin_ctz(w);
            w &= w - 1;
            nbr[off++] = t * 32 + b;
        }
    }
    __syncthreads();

    const int cnt = cnt_s;
    const float grv = gr[i * EMBED + t];
    const float aw = attn_w[t & 31];

    float m = -3e38f;
    float s = 0.f;
    float acc = 0.f;

    // prefetch group 0
    float g[4];
#pragma unroll
    for (int u = 0; u < 4; ++u) {
        int e = u < cnt ? u : 0;
        g[u] = gl[nbr[e] * EMBED + t];
    }

    for (int e0 = 0; e0 < cnt; e0 += 4) {
        float cg[4];
#pragma unroll
        for (int u = 0; u < 4; ++u) cg[u] = g[u];
        // prefetch next group (independent of the update chain below)
#pragma unroll
        for (int u = 0; u < 4; ++u) {
            int e = e0 + 4 + u;
            e = e < cnt ? e : 0;
            g[u] = gl[nbr[e] * EMBED + t];
        }
        // scores: 4 independent shuffle-reduce chains
        float p[4];
#pragma unroll
        for (int u = 0; u < 4; ++u) {
            float x = cg[u] + grv;
            float pv = (x > 0.f ? x : SLOPE * x) * aw;
            pv += __shfl_xor(pv, 1);
            pv += __shfl_xor(pv, 2);
            pv += __shfl_xor(pv, 4);
            pv += __shfl_xor(pv, 8);
            pv += __shfl_xor(pv, 16);
            p[u] = pv;
        }
        // online softmax update (wave-uniform bounds check)
#pragma unroll
        for (int u = 0; u < 4; ++u) {
            if (e0 + u < cnt) {
                float mn = fmaxf(m, p[u]);
                float sc = __expf(m - mn);
                float ev = __expf(p[u] - mn);
                s = s * sc + ev;
                acc = acc * sc + ev * cg[u];
                m = mn;
            }
        }
    }
    out[i * EMBED + t] = acc / s;
}

extern "C" void kernel_launch(void* const* d_in, const int* in_sizes, int n_in,
                              void* d_out, int out_size, void* d_ws, size_t ws_size,
                              hipStream_t stream) {
    const float* h  = (const float*)d_in[0];
    const int*   ei = (const int*)d_in[1];
    const float* Wl = (const float*)d_in[2];
    const float* Wr = (const float*)d_in[3];
    const float* aw = (const float*)d_in[4];
    float* out = (float*)d_out;
    const int E = in_sizes[1] / 2;

    unsigned int* adj = (unsigned int*)d_ws;                 // 128 KB
    float* gl = (float*)((char*)d_ws + 131072);              // 1 MB
    float* gr = gl + NN * EMBED;                             // 1 MB

    k_prep<<<288, 256, 0, stream>>>(h, Wl, Wr, ei, E, gl, gr, adj);
    k_attn<<<NN, 256, 0, stream>>>(gl, gr, adj, aw, out);
}